// Round 8
// baseline (1296.893 us; speedup 1.0000x reference)
//
#include <hip/hip_runtime.h>
#include <math.h>

#define Bb   4
#define Ss   16
#define Nn   2048
#define Ff   32
#define Ee   16384
#define EFf  8
#define Hh   64
#define HB2  32
#define E2c  (Ee + Nn)          // 18432
#define RTOT (Bb*Ss*Nn)         // 131072
#define Mm   (Ss*Nn)            // 32768

__device__ __forceinline__ float sigf(float x) { return 1.f / (1.f + __expf(-x)); }
__device__ __forceinline__ float tanhfast(float x) { return 2.f / (1.f + __expf(-2.f * x)) - 1.f; }

// 64-lane all-reduce sum (R5 version, measured fastest): 4 DPP + swizzle + shfl.
__device__ __forceinline__ float rsum64(float v) {
  int x;
  x = __builtin_amdgcn_update_dpp(0, __float_as_int(v), 0xB1, 0xF, 0xF, true);   // quad_perm xor1
  v += __int_as_float(x);
  x = __builtin_amdgcn_update_dpp(0, __float_as_int(v), 0x4E, 0xF, 0xF, true);   // quad_perm xor2
  v += __int_as_float(x);
  x = __builtin_amdgcn_update_dpp(0, __float_as_int(v), 0x124, 0xF, 0xF, true);  // row_ror:4
  v += __int_as_float(x);
  x = __builtin_amdgcn_update_dpp(0, __float_as_int(v), 0x128, 0xF, 0xF, true);  // row_ror:8
  v += __int_as_float(x);
  x = __builtin_amdgcn_ds_swizzle(__float_as_int(v), 0x401F);                    // xor16
  v += __int_as_float(x);
  v += __shfl_xor(v, 32, 64);                                                    // cross-half
  return v;
}

// ---------------------------------------------------------------------------
__global__ __launch_bounds__(256) void k_loop_accum(
    const int* __restrict__ ei, const float* __restrict__ ea,
    float* __restrict__ cntF, float* __restrict__ loopA) {
  int idx = blockIdx.x * 256 + threadIdx.x;
  int e = idx >> 3, j = idx & 7;
  int d = ei[Ee + e];
  atomicAdd(&loopA[d * EFf + j], ea[idx]);
  if (j == 0) atomicAdd(&cntF[d], 1.0f);
}

__global__ __launch_bounds__(256) void k_loop_div(
    float* __restrict__ loopA, const float* __restrict__ cntF) {
  int idx = blockIdx.x * 256 + threadIdx.x;
  loopA[idx] /= fmaxf(cntF[idx >> 3], 1.0f);
}

// ---------------------------------------------------------------------------
__global__ __launch_bounds__(256) void k_scan(
    const float* __restrict__ cntF, int* __restrict__ offs) {
  __shared__ int partial[256];
  int tid = threadIdx.x;
  int base = tid * 8;
  int vals[8];
  int s = 0;
  for (int i = 0; i < 8; ++i) {
    int c = (int)cntF[base + i] + 1;
    vals[i] = c;
    s += c;
  }
  partial[tid] = s;
  __syncthreads();
  for (int off = 1; off < 256; off <<= 1) {
    int v = partial[tid];
    int add = (tid >= off) ? partial[tid - off] : 0;
    __syncthreads();
    partial[tid] = v + add;
    __syncthreads();
  }
  int run = (tid == 0) ? 0 : partial[tid - 1];
  for (int i = 0; i < 8; ++i) {
    offs[base + i] = run;
    run += vals[i];
  }
  if (tid == 255) offs[Nn] = run;
}

__global__ __launch_bounds__(256) void k_scatter(
    const int* __restrict__ ei, const int* __restrict__ offs,
    int* __restrict__ fillI, int* __restrict__ posOf, int* __restrict__ srcA) {
  int e = blockIdx.x * 256 + threadIdx.x;
  if (e >= E2c) return;
  int d = (e < Ee) ? ei[Ee + e] : (e - Ee);
  int s = (e < Ee) ? ei[e]      : (e - Ee);
  int pos = offs[d] + atomicAdd(&fillI[d], 1);
  posOf[e] = pos;
  srcA[pos] = s;
}

// ---------------------------------------------------------------------------
__global__ __launch_bounds__(256) void k_wtr(
    const float* __restrict__ Wih, const float* __restrict__ Whh,
    float* __restrict__ WT) {
  int idx = blockIdx.x * 256 + threadIdx.x;   // 2*64*384
  int l = idx / (64 * 384);
  int k = (idx / 384) & 63;
  int j = idx % 384;
  float v = (j < 192) ? Wih[((size_t)l * 192 + j) * 64 + k]
                      : Whh[((size_t)l * 192 + (j - 192)) * 64 + k];
  WT[idx] = v;
}

// ---------------------------------------------------------------------------
__global__ __launch_bounds__(256) void k_ep(
    const float* __restrict__ ea, const float* __restrict__ loopA,
    const float* __restrict__ We, const int* __restrict__ posOf,
    float* __restrict__ EPc) {
  __shared__ float wlds[EFf * Hh];
  int tid = threadIdx.x;
  if (tid < EFf * Hh) wlds[tid] = We[tid];
  if (tid + 256 < EFf * Hh) wlds[tid + 256] = We[tid + 256];
  __syncthreads();
  int idx = blockIdx.x * 256 + tid;
  int e = idx >> 6, j = idx & 63;
  const float* a = (e < Ee) ? (ea + (size_t)e * EFf) : (loopA + (size_t)(e - Ee) * EFf);
  float acc = 0.f;
#pragma unroll
  for (int k = 0; k < EFf; ++k) acc += a[k] * wlds[k * Hh + j];
  EPc[(((size_t)posOf[e]) << 6) + j] = acc;
}

// ---------------------------------------------------------------------------
// proj (R5 version, measured fine): thread = 2 rows x 16 cols. grid (RTOT/512,4)
// ---------------------------------------------------------------------------
__global__ __launch_bounds__(256) void k_proj(
    const float* __restrict__ X, const float* __restrict__ Wp,
    const float* __restrict__ bp, float* __restrict__ Out) {
  __shared__ float w[32 * 16];
  int tid = threadIdx.x;
  int j0 = blockIdx.y << 4;
  for (int idx = tid; idx < 32 * 16; idx += 256)
    w[idx] = Wp[((idx >> 4) << 6) + j0 + (idx & 15)];
  __syncthreads();
  int r0 = (blockIdx.x << 9) + tid;
  float acc[2][16];
#pragma unroll
  for (int jj = 0; jj < 16; ++jj) { float b = bp[j0 + jj]; acc[0][jj] = b; acc[1][jj] = b; }
  const float* x0 = X + ((size_t)r0 << 5);
  const float* x1 = x0 + (256 << 5);
  for (int kc = 0; kc < 8; ++kc) {
    float4 a0 = *(const float4*)(x0 + 4 * kc);
    float4 a1 = *(const float4*)(x1 + 4 * kc);
    float a0a[4] = {a0.x, a0.y, a0.z, a0.w};
    float a1a[4] = {a1.x, a1.y, a1.z, a1.w};
#pragma unroll
    for (int q = 0; q < 4; ++q) {
      const float4* wp4 = (const float4*)(w + ((4 * kc + q) << 4));
#pragma unroll
      for (int q4 = 0; q4 < 4; ++q4) {
        float4 wv = wp4[q4];
        acc[0][4*q4+0] = fmaf(a0a[q], wv.x, acc[0][4*q4+0]);
        acc[0][4*q4+1] = fmaf(a0a[q], wv.y, acc[0][4*q4+1]);
        acc[0][4*q4+2] = fmaf(a0a[q], wv.z, acc[0][4*q4+2]);
        acc[0][4*q4+3] = fmaf(a0a[q], wv.w, acc[0][4*q4+3]);
        acc[1][4*q4+0] = fmaf(a1a[q], wv.x, acc[1][4*q4+0]);
        acc[1][4*q4+1] = fmaf(a1a[q], wv.y, acc[1][4*q4+1]);
        acc[1][4*q4+2] = fmaf(a1a[q], wv.z, acc[1][4*q4+2]);
        acc[1][4*q4+3] = fmaf(a1a[q], wv.w, acc[1][4*q4+3]);
      }
    }
  }
#pragma unroll
  for (int rr = 0; rr < 2; ++rr) {
    float* op = Out + (((size_t)(r0 + 256 * rr)) << 6) + j0;
#pragma unroll
    for (int q4 = 0; q4 < 4; ++q4)
      *(float4*)(op + 4 * q4) = make_float4(acc[rr][4*q4], acc[rr][4*q4+1], acc[rr][4*q4+2], acc[rr][4*q4+3]);
  }
}

// ---------------------------------------------------------------------------
// Fused XL/XR v3: A in LDS (stride-65 pad, 1 b32/k/wave), W from global
// (wave-uniform addresses, 8 KB/colgroup -> L1/sK-cache resident).
// block = 128 rows x 2 colgroups(16). grid (RTOT/128, 2).
// ---------------------------------------------------------------------------
__global__ __launch_bounds__(256) void k_xlr(
    const float* __restrict__ X,
    const float* __restrict__ Wl_, const float* __restrict__ bl_,
    const float* __restrict__ Wr_, const float* __restrict__ br_,
    float* __restrict__ XL, float* __restrict__ XR) {
  __shared__ float xa[128 * 65];
  int tid = threadIdx.x;
  int r = tid & 127;
  int grp = tid >> 7;                  // 0..1
  int j0 = (blockIdx.y << 5) + (grp << 4);
  size_t rowbase = (size_t)blockIdx.x << 7;
  // stage A coalesced
  {
    const float* src = X + (rowbase << 6);
    for (int i = tid; i < 128 * 64; i += 256)
      xa[(i >> 6) * 65 + (i & 63)] = src[i];
  }
  __syncthreads();
  float accL[16], accR[16];
#pragma unroll
  for (int jj = 0; jj < 16; ++jj) { accL[jj] = bl_[j0 + jj]; accR[jj] = br_[j0 + jj]; }
  const float* ar = xa + r * 65;
#pragma unroll 4
  for (int k = 0; k < 64; ++k) {
    float a = ar[k];
    const float4* wL = (const float4*)(Wl_ + (k << 6) + j0);
    const float4* wR = (const float4*)(Wr_ + (k << 6) + j0);
#pragma unroll
    for (int q4 = 0; q4 < 4; ++q4) {
      float4 lv = wL[q4], rv = wR[q4];
      accL[4*q4+0] = fmaf(a, lv.x, accL[4*q4+0]);
      accL[4*q4+1] = fmaf(a, lv.y, accL[4*q4+1]);
      accL[4*q4+2] = fmaf(a, lv.z, accL[4*q4+2]);
      accL[4*q4+3] = fmaf(a, lv.w, accL[4*q4+3]);
      accR[4*q4+0] = fmaf(a, rv.x, accR[4*q4+0]);
      accR[4*q4+1] = fmaf(a, rv.y, accR[4*q4+1]);
      accR[4*q4+2] = fmaf(a, rv.z, accR[4*q4+2]);
      accR[4*q4+3] = fmaf(a, rv.w, accR[4*q4+3]);
    }
  }
  size_t ob = ((rowbase + r) << 6) + j0;   // lane writes 64B line (16 floats)
#pragma unroll
  for (int q4 = 0; q4 < 4; ++q4) {
    *(float4*)(XL + ob + 4 * q4) = make_float4(accL[4*q4], accL[4*q4+1], accL[4*q4+2], accL[4*q4+3]);
    *(float4*)(XR + ob + 4 * q4) = make_float4(accR[4*q4], accR[4*q4+1], accR[4*q4+2], accR[4*q4+3]);
  }
}

// ---------------------------------------------------------------------------
// GATv2 (R5 version, measured 83 us): wave per (g,d), lane = h.
// ---------------------------------------------------------------------------
__global__ __launch_bounds__(256) void k_gat(
    const float* __restrict__ XL, float* __restrict__ XR_HG,
    const float* __restrict__ EPc, const int* __restrict__ offs,
    const int* __restrict__ srcA,
    const float* __restrict__ att, const float* __restrict__ gbl) {
  int gw = (blockIdx.x * 256 + threadIdx.x) >> 6;
  int lane = threadIdx.x & 63;
  int g = gw >> 11;
  int d = gw & (Nn - 1);
  float attv = att[lane];
  float gbv = gbl[lane];
  size_t rowbase = ((size_t)gw) << 6;
  float xr = XR_HG[rowbase + lane];
  int p0 = offs[d], p1 = offs[d + 1];
  int nE = p1 - p0;
  int nE4 = nE < 64 ? nE : 64;
  int soff = 0;
  if (lane < nE4) soff = srcA[p0 + lane] << 8;           // byte offset of src row
  const char* XLg = (const char*)(XL + (((size_t)g * Nn) << 6)) + (lane << 2);
  const char* EPp = (const char*)(EPc + (((size_t)p0) << 6)) + (lane << 2);
  float Ssum = 0.f, acc = 0.f;
  int nCh = (nE4 + 7) >> 3;
  for (int c = 0; c < nCh; ++c) {
    int p = c << 3;
    float xl[8], vv[8];
#pragma unroll
    for (int u = 0; u < 8; ++u) {
      int pu = p + u;
      int pc = pu < nE4 ? pu : nE4 - 1;                  // clamp (masked later)
      int so = __shfl(soff, pc, 64);
      xl[u] = *(const float*)(XLg + so);
      float ep = *(const float*)(EPp + (pc << 8));
      float m = xl[u] + xr + ep;
      m = fmaxf(m, 0.2f * m);                            // leaky_relu(0.2)
      vv[u] = m * attv;
    }
#pragma unroll
    for (int u = 0; u < 8; ++u) vv[u] = rsum64(vv[u]);
#pragma unroll
    for (int u = 0; u < 8; ++u) {
      float v = (p + u < nE4) ? vv[u] : -1e30f;
      float w = __expf(v);
      Ssum += w;
      acc = fmaf(w, xl[u], acc);
    }
  }
  for (int p = 64; p < nE; ++p) {                        // pathological tail
    int s = srcA[p0 + p];
    float xlv = *(const float*)(XLg + (s << 8));
    float ep = *(const float*)(EPp + (p << 8));
    float m = xlv + xr + ep; m = fmaxf(m, 0.2f * m);
    float w = __expf(rsum64(m * attv));
    Ssum += w; acc = fmaf(w, xlv, acc);
  }
  XR_HG[rowbase + lane] = acc / Ssum + gbv;
}

// ---------------------------------------------------------------------------
// Per-t fused GRU v3: A (hg,hp) in LDS (2 b32/k/wave), W from global
// (wave-uniform, 12 KB/colgroup -> cache-resident).
// block = 64 rows x 4 colgroups(8 hcols, all 6 gates). grid (Mm/64, 2).
// ---------------------------------------------------------------------------
template <int HASP>
__global__ __launch_bounds__(256) void k_gru_t(
    const float* __restrict__ hg, const float* __restrict__ hp,
    const float* __restrict__ WTl,   // [64][384]: cols 0..191 ih(r,z,n), 192..383 hh
    const float* __restrict__ bih, const float* __restrict__ bhh,
    float* __restrict__ hout) {
  __shared__ float hgl[64 * 65];
  __shared__ float hpl[64 * 65];
  int tid = threadIdx.x;
  int r = tid & 63;
  int grp = tid >> 6;                  // 0..3
  int j0 = (blockIdx.y << 5) + (grp << 3);
  size_t rowbase = (size_t)blockIdx.x << 6;
  {
    const float* sg = hg + (rowbase << 6);
    for (int i = tid; i < 64 * 64; i += 256)
      hgl[(i >> 6) * 65 + (i & 63)] = sg[i];
    if (HASP) {
      const float* sp = hp + (rowbase << 6);
      for (int i = tid; i < 64 * 64; i += 256)
        hpl[(i >> 6) * 65 + (i & 63)] = sp[i];
    }
  }
  __syncthreads();
  float acc[6][8];
#pragma unroll
  for (int gg = 0; gg < 3; ++gg)
#pragma unroll
    for (int c = 0; c < 8; ++c) {
      acc[gg][c]     = bih[(gg << 6) + j0 + c];
      acc[3 + gg][c] = bhh[(gg << 6) + j0 + c];
    }
  const float* agr = hgl + r * 65;
  const float* apr = hpl + r * 65;
#pragma unroll 2
  for (int k = 0; k < 64; ++k) {
    float ag = agr[k];
    const float* wk = WTl + k * 384 + j0;
#pragma unroll
    for (int gg = 0; gg < 3; ++gg) {
      float4 w0 = *(const float4*)(wk + (gg << 6));
      float4 w1 = *(const float4*)(wk + (gg << 6) + 4);
      acc[gg][0] = fmaf(ag, w0.x, acc[gg][0]);
      acc[gg][1] = fmaf(ag, w0.y, acc[gg][1]);
      acc[gg][2] = fmaf(ag, w0.z, acc[gg][2]);
      acc[gg][3] = fmaf(ag, w0.w, acc[gg][3]);
      acc[gg][4] = fmaf(ag, w1.x, acc[gg][4]);
      acc[gg][5] = fmaf(ag, w1.y, acc[gg][5]);
      acc[gg][6] = fmaf(ag, w1.z, acc[gg][6]);
      acc[gg][7] = fmaf(ag, w1.w, acc[gg][7]);
    }
    if (HASP) {
      float ap = apr[k];
#pragma unroll
      for (int gg = 0; gg < 3; ++gg) {
        float4 w0 = *(const float4*)(wk + 192 + (gg << 6));
        float4 w1 = *(const float4*)(wk + 192 + (gg << 6) + 4);
        acc[3+gg][0] = fmaf(ap, w0.x, acc[3+gg][0]);
        acc[3+gg][1] = fmaf(ap, w0.y, acc[3+gg][1]);
        acc[3+gg][2] = fmaf(ap, w0.z, acc[3+gg][2]);
        acc[3+gg][3] = fmaf(ap, w0.w, acc[3+gg][3]);
        acc[3+gg][4] = fmaf(ap, w1.x, acc[3+gg][4]);
        acc[3+gg][5] = fmaf(ap, w1.y, acc[3+gg][5]);
        acc[3+gg][6] = fmaf(ap, w1.z, acc[3+gg][6]);
        acc[3+gg][7] = fmaf(ap, w1.w, acc[3+gg][7]);
      }
    }
  }
  float o[8];
#pragma unroll
  for (int c = 0; c < 8; ++c) {
    float rg = sigf(acc[0][c] + acc[3][c]);
    float zg = sigf(acc[1][c] + acc[4][c]);
    float ng = tanhfast(acc[2][c] + rg * acc[5][c]);
    float hv = HASP ? apr[j0 + c] : 0.f;
    o[c] = (1.f - zg) * ng + zg * hv;
  }
  float* op = hout + ((rowbase + r) << 6) + j0;
  *(float4*)(op)     = make_float4(o[0], o[1], o[2], o[3]);
  *(float4*)(op + 4) = make_float4(o[4], o[5], o[6], o[7]);
}

// ---------------------------------------------------------------------------
__global__ __launch_bounds__(256) void k_heads(
    const float* __restrict__ Xb,
    const float* __restrict__ oW1, const float* __restrict__ ob1,
    const float* __restrict__ oW2, const float* __restrict__ ob2,
    const float* __restrict__ dW1, const float* __restrict__ db1,
    const float* __restrict__ dW2, const float* __restrict__ db2,
    float* __restrict__ out) {
  __shared__ float w1o[Hh * HB2], w1d[Hh * HB2];
  __shared__ float w2o[HB2], w2d[HB2], b1o[HB2], b1d[HB2];
  int tid = threadIdx.x;
  for (int idx = tid; idx < Hh * HB2; idx += 256) { w1o[idx] = oW1[idx]; w1d[idx] = dW1[idx]; }
  if (tid < HB2) { w2o[tid] = oW2[tid]; w2d[tid] = dW2[tid]; b1o[tid] = ob1[tid]; b1d[tid] = db1[tid]; }
  __syncthreads();
  int r = blockIdx.x * 256 + tid;
  int b = r >> 11, n = r & (Nn - 1);
  const float* xrow = Xb + (((size_t)b * Ss + (Ss - 1)) * Nn + n) * Hh;
  float x[Hh];
  const float4* xp = (const float4*)xrow;
#pragma unroll
  for (int q = 0; q < Hh / 4; ++q) {
    float4 v = xp[q];
    x[4*q] = v.x; x[4*q+1] = v.y; x[4*q+2] = v.z; x[4*q+3] = v.w;
  }
  float acco = ob2[0], accd = db2[0];
  for (int j = 0; j < HB2; ++j) {
    float ho = b1o[j], hd = b1d[j];
#pragma unroll
    for (int k = 0; k < Hh; ++k) {
      ho += x[k] * w1o[k * HB2 + j];
      hd += x[k] * w1d[k * HB2 + j];
    }
    acco += fmaxf(ho, 0.f) * w2o[j];
    accd += fmaxf(hd, 0.f) * w2d[j];
  }
  out[r] = acco;
  out[Bb * Nn + r] = accd;
}

// ---------------------------------------------------------------------------
extern "C" void kernel_launch(void* const* d_in, const int* in_sizes, int n_in,
                              void* d_out, int out_size, void* d_ws, size_t ws_size,
                              hipStream_t stream) {
  const float* x   = (const float*)d_in[0];
  const int*   ei  = (const int*)d_in[1];
  const float* ea  = (const float*)d_in[2];
  const float* Wp  = (const float*)d_in[3];
  const float* bp  = (const float*)d_in[4];
  const float* Wl  = (const float*)d_in[5];
  const float* bl  = (const float*)d_in[6];
  const float* Wr  = (const float*)d_in[7];
  const float* br  = (const float*)d_in[8];
  const float* We  = (const float*)d_in[9];
  const float* att = (const float*)d_in[10];
  const float* gb  = (const float*)d_in[11];
  const float* Wih = (const float*)d_in[12];
  const float* Whh = (const float*)d_in[13];
  const float* bih = (const float*)d_in[14];
  const float* bhh = (const float*)d_in[15];
  const float* oW1 = (const float*)d_in[16];
  const float* ob1 = (const float*)d_in[17];
  const float* oW2 = (const float*)d_in[18];
  const float* ob2 = (const float*)d_in[19];
  const float* dW1 = (const float*)d_in[20];
  const float* db1 = (const float*)d_in[21];
  const float* dW2 = (const float*)d_in[22];
  const float* db2 = (const float*)d_in[23];
  float* out = (float*)d_out;

  // workspace layout (floats)
  float* f    = (float*)d_ws;
  float* Xb   = f;                          // 131072*64
  float* XLb  = Xb  + (size_t)RTOT * Hh;    // 131072*64
  float* XRb  = XLb + (size_t)RTOT * Hh;    // 131072*64 (hg after k_gat)
  float* EPc  = XRb + (size_t)RTOT * Hh;    // 18432*64 (CSR order)
  float* WTb  = EPc + (size_t)E2c * Hh;     // 2*64*384
  float* cntF = WTb + 2 * 64 * 384;         // 2048
  float* loopA = cntF + Nn;                 // 2048*8
  int*   fillI = (int*)(loopA + Nn * EFf);  // 2048
  int*   offs  = fillI + Nn;                // 2049 (+pad)
  int*   posOf = offs + 2052;               // 18432
  int*   srcA  = posOf + E2c;               // 18432

  hipMemsetAsync(cntF, 0, (size_t)(Nn + Nn * EFf + Nn) * 4, stream);

  k_loop_accum<<<dim3(Ee * EFf / 256), 256, 0, stream>>>(ei, ea, cntF, loopA);
  k_loop_div<<<dim3(Nn * EFf / 256), 256, 0, stream>>>(loopA, cntF);
  k_scan<<<1, 256, 0, stream>>>(cntF, offs);
  k_scatter<<<dim3((E2c + 255) / 256), 256, 0, stream>>>(ei, offs, fillI, posOf, srcA);
  k_wtr<<<dim3(2 * 64 * 384 / 256), 256, 0, stream>>>(Wih, Whh, WTb);

  // X = x @ Wp + bp
  k_proj<<<dim3(RTOT / 512, 4), 256, 0, stream>>>(x, Wp, bp, Xb);

  for (int l = 0; l < 2; ++l) {
    k_ep<<<dim3(E2c * Hh / 256), 256, 0, stream>>>(
        ea, loopA, We + (size_t)l * EFf * Hh, posOf, EPc);
    k_xlr<<<dim3(RTOT / 128, 2), 256, 0, stream>>>(
        Xb, Wl + (size_t)l * Hh * Hh, bl + (size_t)l * Hh,
        Wr + (size_t)l * Hh * Hh, br + (size_t)l * Hh, XLb, XRb);
    k_gat<<<dim3(RTOT * Hh / 256), 256, 0, stream>>>(
        XLb, XRb, EPc, offs, srcA, att + (size_t)l * Hh, gb + (size_t)l * Hh);
    const float* WTl = WTb + (size_t)l * 64 * 384;
    const float* bih_l = bih + (size_t)l * 192;
    const float* bhh_l = bhh + (size_t)l * 192;
    for (int t = 0; t < Bb; ++t) {
      const float* hg_t = XRb + (size_t)t * Mm * Hh;
      float* h_out = Xb + (size_t)t * Mm * Hh;
      if (t == 0) {
        k_gru_t<0><<<dim3(Mm / 64, 2), 256, 0, stream>>>(
            hg_t, nullptr, WTl, bih_l, bhh_l, h_out);
      } else {
        const float* h_prev = Xb + (size_t)(t - 1) * Mm * Hh;
        k_gru_t<1><<<dim3(Mm / 64, 2), 256, 0, stream>>>(
            hg_t, h_prev, WTl, bih_l, bhh_l, h_out);
      }
    }
  }

  k_heads<<<dim3(Bb * Nn / 256), 256, 0, stream>>>(
      Xb, oW1, ob1, oW2, ob2, dW1, db1, dW2, db2, out);
}

// Round 9
// 506.714 us; speedup vs baseline: 2.5594x; 2.5594x over previous
//
#include <hip/hip_runtime.h>
#include <math.h>

#define Bb   4
#define Ss   16
#define Nn   2048
#define Ff   32
#define Ee   16384
#define EFf  8
#define Hh   64
#define HB2  32
#define E2c  (Ee + Nn)          // 18432
#define RTOT (Bb*Ss*Nn)         // 131072
#define Mm   (Ss*Nn)            // 32768

typedef __attribute__((ext_vector_type(8))) short short8;
typedef __attribute__((ext_vector_type(4))) float f32x4;
#define MFMA16 __builtin_amdgcn_mfma_f32_16x16x32_bf16

__device__ __forceinline__ float sigf(float x) { return 1.f / (1.f + __expf(-x)); }
__device__ __forceinline__ float tanhfast(float x) { return 2.f / (1.f + __expf(-2.f * x)) - 1.f; }

// round-to-nearest-even bf16 split: x ~= hi + lo (each bf16)
__device__ __forceinline__ void split_bf16(float x, unsigned short& h, unsigned short& l) {
  unsigned u = __float_as_uint(x);
  unsigned r = (u + 0x7FFFu + ((u >> 16) & 1u)) >> 16;
  h = (unsigned short)r;
  float rest = x - __uint_as_float(r << 16);
  unsigned u2 = __float_as_uint(rest);
  l = (unsigned short)((u2 + 0x7FFFu + ((u2 >> 16) & 1u)) >> 16);
}

// 64-lane all-reduce sum (R5 version, measured fastest)
__device__ __forceinline__ float rsum64(float v) {
  int x;
  x = __builtin_amdgcn_update_dpp(0, __float_as_int(v), 0xB1, 0xF, 0xF, true);
  v += __int_as_float(x);
  x = __builtin_amdgcn_update_dpp(0, __float_as_int(v), 0x4E, 0xF, 0xF, true);
  v += __int_as_float(x);
  x = __builtin_amdgcn_update_dpp(0, __float_as_int(v), 0x124, 0xF, 0xF, true);
  v += __int_as_float(x);
  x = __builtin_amdgcn_update_dpp(0, __float_as_int(v), 0x128, 0xF, 0xF, true);
  v += __int_as_float(x);
  x = __builtin_amdgcn_ds_swizzle(__float_as_int(v), 0x401F);
  v += __int_as_float(x);
  v += __shfl_xor(v, 32, 64);
  return v;
}

// ---------------------------------------------------------------------------
__global__ __launch_bounds__(256) void k_loop_accum(
    const int* __restrict__ ei, const float* __restrict__ ea,
    float* __restrict__ cntF, float* __restrict__ loopA) {
  int idx = blockIdx.x * 256 + threadIdx.x;
  int e = idx >> 3, j = idx & 7;
  int d = ei[Ee + e];
  atomicAdd(&loopA[d * EFf + j], ea[idx]);
  if (j == 0) atomicAdd(&cntF[d], 1.0f);
}

__global__ __launch_bounds__(256) void k_loop_div(
    float* __restrict__ loopA, const float* __restrict__ cntF) {
  int idx = blockIdx.x * 256 + threadIdx.x;
  loopA[idx] /= fmaxf(cntF[idx >> 3], 1.0f);
}

// ---------------------------------------------------------------------------
__global__ __launch_bounds__(256) void k_scan(
    const float* __restrict__ cntF, int* __restrict__ offs) {
  __shared__ int partial[256];
  int tid = threadIdx.x;
  int base = tid * 8;
  int vals[8];
  int s = 0;
  for (int i = 0; i < 8; ++i) {
    int c = (int)cntF[base + i] + 1;
    vals[i] = c;
    s += c;
  }
  partial[tid] = s;
  __syncthreads();
  for (int off = 1; off < 256; off <<= 1) {
    int v = partial[tid];
    int add = (tid >= off) ? partial[tid - off] : 0;
    __syncthreads();
    partial[tid] = v + add;
    __syncthreads();
  }
  int run = (tid == 0) ? 0 : partial[tid - 1];
  for (int i = 0; i < 8; ++i) {
    offs[base + i] = run;
    run += vals[i];
  }
  if (tid == 255) offs[Nn] = run;
}

__global__ __launch_bounds__(256) void k_scatter(
    const int* __restrict__ ei, const int* __restrict__ offs,
    int* __restrict__ fillI, int* __restrict__ posOf, int* __restrict__ srcA) {
  int e = blockIdx.x * 256 + threadIdx.x;
  if (e >= E2c) return;
  int d = (e < Ee) ? ei[Ee + e] : (e - Ee);
  int s = (e < Ee) ? ei[e]      : (e - Ee);
  int pos = offs[d] + atomicAdd(&fillI[d], 1);
  posOf[e] = pos;
  srcA[pos] = s;
}

// ---------------------------------------------------------------------------
// Pre-split + pre-swizzle weights into MFMA B-fragment order.
// xlr: [2l][8t][2kh][64lane][8j]  (n = t*16+(lane&15); k = kh*32+(lane>>4)*8+j)
//      n<64 -> Wl[k][n], else Wr[k][n-64]
// gru: [2l][24t][2kh][64lane][8j] (n in [0,384): g=n>>6, c=n&63)
//      g<3 -> Wih[g*64+c][k], else Whh[(g-3)*64+c][k]
// ---------------------------------------------------------------------------
__global__ __launch_bounds__(256) void k_wprep(
    const float* __restrict__ Wl, const float* __restrict__ Wr,
    const float* __restrict__ Wih, const float* __restrict__ Whh,
    unsigned short* __restrict__ WXhi, unsigned short* __restrict__ WXlo,
    unsigned short* __restrict__ WGhi, unsigned short* __restrict__ WGlo) {
  int idx = blockIdx.x * 256 + threadIdx.x;   // 65536 total
  if (idx < 16384) {
    int j = idx & 7, lane = (idx >> 3) & 63, kh = (idx >> 9) & 1;
    int t = (idx >> 10) & 7, l = idx >> 13;
    int n = t * 16 + (lane & 15);
    int k = kh * 32 + ((lane >> 4) << 3) + j;
    const float* W = (n < 64) ? (Wl + (size_t)l * 4096) : (Wr + (size_t)l * 4096);
    float v = W[k * 64 + (n & 63)];
    unsigned short h, lo;
    split_bf16(v, h, lo);
    WXhi[idx] = h; WXlo[idx] = lo;
  } else {
    int i2 = idx - 16384;                     // < 49152
    int j = i2 & 7, lane = (i2 >> 3) & 63, kh = (i2 >> 9) & 1;
    int t = (i2 >> 10) % 24, l = i2 / 24576;
    int n = t * 16 + (lane & 15);
    int k = kh * 32 + ((lane >> 4) << 3) + j;
    int g = n >> 6, c = n & 63;
    const float* W = (g < 3) ? (Wih + (size_t)l * 12288 + (size_t)(g * 64 + c) * 64)
                             : (Whh + (size_t)l * 12288 + (size_t)((g - 3) * 64 + c) * 64);
    float v = W[k];
    unsigned short h, lo;
    split_bf16(v, h, lo);
    WGhi[i2] = h; WGlo[i2] = lo;
  }
}

// ---------------------------------------------------------------------------
__global__ __launch_bounds__(256) void k_ep(
    const float* __restrict__ ea, const float* __restrict__ loopA,
    const float* __restrict__ We, const int* __restrict__ posOf,
    float* __restrict__ EPc) {
  __shared__ float wlds[EFf * Hh];
  int tid = threadIdx.x;
  if (tid < EFf * Hh) wlds[tid] = We[tid];
  if (tid + 256 < EFf * Hh) wlds[tid + 256] = We[tid + 256];
  __syncthreads();
  int idx = blockIdx.x * 256 + tid;
  int e = idx >> 6, j = idx & 63;
  const float* a = (e < Ee) ? (ea + (size_t)e * EFf) : (loopA + (size_t)(e - Ee) * EFf);
  float acc = 0.f;
#pragma unroll
  for (int k = 0; k < EFf; ++k) acc += a[k] * wlds[k * Hh + j];
  EPc[(((size_t)posOf[e]) << 6) + j] = acc;
}

// ---------------------------------------------------------------------------
// proj (R5 version): thread = 2 rows x 16 cols. grid (RTOT/512, 4)
// ---------------------------------------------------------------------------
__global__ __launch_bounds__(256) void k_proj(
    const float* __restrict__ X, const float* __restrict__ Wp,
    const float* __restrict__ bp, float* __restrict__ Out) {
  __shared__ float w[32 * 16];
  int tid = threadIdx.x;
  int j0 = blockIdx.y << 4;
  for (int idx = tid; idx < 32 * 16; idx += 256)
    w[idx] = Wp[((idx >> 4) << 6) + j0 + (idx & 15)];
  __syncthreads();
  int r0 = (blockIdx.x << 9) + tid;
  float acc[2][16];
#pragma unroll
  for (int jj = 0; jj < 16; ++jj) { float b = bp[j0 + jj]; acc[0][jj] = b; acc[1][jj] = b; }
  const float* x0 = X + ((size_t)r0 << 5);
  const float* x1 = x0 + (256 << 5);
  for (int kc = 0; kc < 8; ++kc) {
    float4 a0 = *(const float4*)(x0 + 4 * kc);
    float4 a1 = *(const float4*)(x1 + 4 * kc);
    float a0a[4] = {a0.x, a0.y, a0.z, a0.w};
    float a1a[4] = {a1.x, a1.y, a1.z, a1.w};
#pragma unroll
    for (int q = 0; q < 4; ++q) {
      const float4* wp4 = (const float4*)(w + ((4 * kc + q) << 4));
#pragma unroll
      for (int q4 = 0; q4 < 4; ++q4) {
        float4 wv = wp4[q4];
        acc[0][4*q4+0] = fmaf(a0a[q], wv.x, acc[0][4*q4+0]);
        acc[0][4*q4+1] = fmaf(a0a[q], wv.y, acc[0][4*q4+1]);
        acc[0][4*q4+2] = fmaf(a0a[q], wv.z, acc[0][4*q4+2]);
        acc[0][4*q4+3] = fmaf(a0a[q], wv.w, acc[0][4*q4+3]);
        acc[1][4*q4+0] = fmaf(a1a[q], wv.x, acc[1][4*q4+0]);
        acc[1][4*q4+1] = fmaf(a1a[q], wv.y, acc[1][4*q4+1]);
        acc[1][4*q4+2] = fmaf(a1a[q], wv.z, acc[1][4*q4+2]);
        acc[1][4*q4+3] = fmaf(a1a[q], wv.w, acc[1][4*q4+3]);
      }
    }
  }
#pragma unroll
  for (int rr = 0; rr < 2; ++rr) {
    float* op = Out + (((size_t)(r0 + 256 * rr)) << 6) + j0;
#pragma unroll
    for (int q4 = 0; q4 < 4; ++q4)
      *(float4*)(op + 4 * q4) = make_float4(acc[rr][4*q4], acc[rr][4*q4+1], acc[rr][4*q4+2], acc[rr][4*q4+3]);
  }
}

// ---------------------------------------------------------------------------
// XL/XR via bf16x3 MFMA. Block = 64 rows; wave = one 16-row m-tile; 8 n-tiles
// (N=128: n<64 -> XL, else XR). A staged through LDS in fragment order.
// ---------------------------------------------------------------------------
__global__ __launch_bounds__(256) void k_xlr_mm(
    const float* __restrict__ X,
    const unsigned short* __restrict__ WXhi, const unsigned short* __restrict__ WXlo,
    const float* __restrict__ bl_, const float* __restrict__ br_,
    float* __restrict__ XL, float* __restrict__ XR) {
  __shared__ unsigned short ahi[4096], alo[4096];
  int tid = threadIdx.x, lane = tid & 63, wv = tid >> 6;
  size_t m0 = (size_t)blockIdx.x << 6;
  for (int i = 0; i < 16; ++i) {
    int el = (i << 8) + tid, row = el >> 6, c = el & 63;
    float x = X[((m0 + row) << 6) + c];
    unsigned short h, lo;
    split_bf16(x, h, lo);
    int fa = ((((c >> 5) << 2) + (row >> 4)) * 64 + (((c >> 3) & 3) << 4) + (row & 15)) * 8 + (c & 7);
    ahi[fa] = h; alo[fa] = lo;
  }
  __syncthreads();
  short8 Ah0 = *(const short8*)&ahi[((0 + wv) << 6 | lane) << 3];
  short8 Al0 = *(const short8*)&alo[((0 + wv) << 6 | lane) << 3];
  short8 Ah1 = *(const short8*)&ahi[((4 + wv) << 6 | lane) << 3];
  short8 Al1 = *(const short8*)&alo[((4 + wv) << 6 | lane) << 3];
  int nl = lane & 15;
  f32x4 acc[8];
#pragma unroll
  for (int t = 0; t < 8; ++t) {
    int n = t * 16 + nl;
    float b = (n < 64) ? bl_[n] : br_[n - 64];
    acc[t] = (f32x4){b, b, b, b};
  }
#pragma unroll
  for (int t = 0; t < 8; ++t) {
    const short8* bh0p = (const short8*)(WXhi + ((t << 1) << 9)) + lane;
    const short8* bl0p = (const short8*)(WXlo + ((t << 1) << 9)) + lane;
    const short8* bh1p = (const short8*)(WXhi + (((t << 1) + 1) << 9)) + lane;
    const short8* bl1p = (const short8*)(WXlo + (((t << 1) + 1) << 9)) + lane;
    short8 bh0 = *bh0p, bl0 = *bl0p, bh1 = *bh1p, bl1 = *bl1p;
    acc[t] = MFMA16(Ah0, bh0, acc[t], 0, 0, 0);
    acc[t] = MFMA16(Ah0, bl0, acc[t], 0, 0, 0);
    acc[t] = MFMA16(Al0, bh0, acc[t], 0, 0, 0);
    acc[t] = MFMA16(Ah1, bh1, acc[t], 0, 0, 0);
    acc[t] = MFMA16(Ah1, bl1, acc[t], 0, 0, 0);
    acc[t] = MFMA16(Al1, bh1, acc[t], 0, 0, 0);
  }
  int rbase = (wv << 4) + ((lane >> 4) << 2);
#pragma unroll
  for (int t = 0; t < 8; ++t) {
    int n = t * 16 + nl;
    float* out = (n < 64) ? (XL + (m0 << 6) + n) : (XR + (m0 << 6) + (n - 64));
#pragma unroll
    for (int reg = 0; reg < 4; ++reg)
      out[(size_t)(rbase + reg) << 6] = acc[t][reg];
  }
}

// ---------------------------------------------------------------------------
// GATv2 (R5 version, measured 83 us): wave per (g,d), lane = h.
// ---------------------------------------------------------------------------
__global__ __launch_bounds__(256) void k_gat(
    const float* __restrict__ XL, float* __restrict__ XR_HG,
    const float* __restrict__ EPc, const int* __restrict__ offs,
    const int* __restrict__ srcA,
    const float* __restrict__ att, const float* __restrict__ gbl) {
  int gw = (blockIdx.x * 256 + threadIdx.x) >> 6;
  int lane = threadIdx.x & 63;
  int g = gw >> 11;
  int d = gw & (Nn - 1);
  float attv = att[lane];
  float gbv = gbl[lane];
  size_t rowbase = ((size_t)gw) << 6;
  float xr = XR_HG[rowbase + lane];
  int p0 = offs[d], p1 = offs[d + 1];
  int nE = p1 - p0;
  int nE4 = nE < 64 ? nE : 64;
  int soff = 0;
  if (lane < nE4) soff = srcA[p0 + lane] << 8;
  const char* XLg = (const char*)(XL + (((size_t)g * Nn) << 6)) + (lane << 2);
  const char* EPp = (const char*)(EPc + (((size_t)p0) << 6)) + (lane << 2);
  float Ssum = 0.f, acc = 0.f;
  int nCh = (nE4 + 7) >> 3;
  for (int c = 0; c < nCh; ++c) {
    int p = c << 3;
    float xl[8], vv[8];
#pragma unroll
    for (int u = 0; u < 8; ++u) {
      int pu = p + u;
      int pc = pu < nE4 ? pu : nE4 - 1;
      int so = __shfl(soff, pc, 64);
      xl[u] = *(const float*)(XLg + so);
      float ep = *(const float*)(EPp + (pc << 8));
      float m = xl[u] + xr + ep;
      m = fmaxf(m, 0.2f * m);
      vv[u] = m * attv;
    }
#pragma unroll
    for (int u = 0; u < 8; ++u) vv[u] = rsum64(vv[u]);
#pragma unroll
    for (int u = 0; u < 8; ++u) {
      float v = (p + u < nE4) ? vv[u] : -1e30f;
      float w = __expf(v);
      Ssum += w;
      acc = fmaf(w, xl[u], acc);
    }
  }
  for (int p = 64; p < nE; ++p) {
    int s = srcA[p0 + p];
    float xlv = *(const float*)(XLg + (s << 8));
    float ep = *(const float*)(EPp + (p << 8));
    float m = xlv + xr + ep; m = fmaxf(m, 0.2f * m);
    float w = __expf(rsum64(m * attv));
    Ssum += w; acc = fmaf(w, xlv, acc);
  }
  XR_HG[rowbase + lane] = acc / Ssum + gbv;
}

// ---------------------------------------------------------------------------
// Fused GRU step via bf16x3 MFMA. Block = 64 rows; wave = 16-row m-tile.
// 24 n-tiles over W=[gi_r|gi_z|gi_n|gh_r|gh_z|gh_n] (N=384). Gate combine is
// lane-local (all 6 gate tiles share (lane,reg) position). h written direct.
// ---------------------------------------------------------------------------
template <int HASP>
__global__ __launch_bounds__(256) void k_gru_mm(
    const float* __restrict__ hg, const float* __restrict__ hp,
    const unsigned short* __restrict__ WGhi, const unsigned short* __restrict__ WGlo,
    const float* __restrict__ bih, const float* __restrict__ bhh,
    float* __restrict__ hout) {
  __shared__ unsigned short ghi[4096], glo[4096], phi[4096], plo[4096];
  int tid = threadIdx.x, lane = tid & 63, wv = tid >> 6;
  size_t m0 = (size_t)blockIdx.x << 6;
  for (int i = 0; i < 16; ++i) {
    int el = (i << 8) + tid, row = el >> 6, c = el & 63;
    int fa = ((((c >> 5) << 2) + (row >> 4)) * 64 + (((c >> 3) & 3) << 4) + (row & 15)) * 8 + (c & 7);
    float xg = hg[((m0 + row) << 6) + c];
    unsigned short h, lo;
    split_bf16(xg, h, lo);
    ghi[fa] = h; glo[fa] = lo;
    if (HASP) {
      float xp = hp[((m0 + row) << 6) + c];
      split_bf16(xp, h, lo);
      phi[fa] = h; plo[fa] = lo;
    }
  }
  __syncthreads();
  short8 Gh0 = *(const short8*)&ghi[((0 + wv) << 6 | lane) << 3];
  short8 Gl0 = *(const short8*)&glo[((0 + wv) << 6 | lane) << 3];
  short8 Gh1 = *(const short8*)&ghi[((4 + wv) << 6 | lane) << 3];
  short8 Gl1 = *(const short8*)&glo[((4 + wv) << 6 | lane) << 3];
  short8 Ph0, Pl0, Ph1, Pl1;
  if (HASP) {
    Ph0 = *(const short8*)&phi[((0 + wv) << 6 | lane) << 3];
    Pl0 = *(const short8*)&plo[((0 + wv) << 6 | lane) << 3];
    Ph1 = *(const short8*)&phi[((4 + wv) << 6 | lane) << 3];
    Pl1 = *(const short8*)&plo[((4 + wv) << 6 | lane) << 3];
  }
  int nl = lane & 15;
  f32x4 acc[24];
#pragma unroll
  for (int t = 0; t < 24; ++t) {
    int g = t >> 2;
    int c = ((t & 3) << 4) + nl;
    float b = (g < 3) ? bih[(g << 6) + c] : bhh[((g - 3) << 6) + c];
    acc[t] = (f32x4){b, b, b, b};
  }
#pragma unroll
  for (int t = 0; t < 12; ++t) {
    const short8* bh0p = (const short8*)(WGhi + ((t << 1) << 9)) + lane;
    const short8* bl0p = (const short8*)(WGlo + ((t << 1) << 9)) + lane;
    const short8* bh1p = (const short8*)(WGhi + (((t << 1) + 1) << 9)) + lane;
    const short8* bl1p = (const short8*)(WGlo + (((t << 1) + 1) << 9)) + lane;
    short8 bh0 = *bh0p, bl0 = *bl0p, bh1 = *bh1p, bl1 = *bl1p;
    acc[t] = MFMA16(Gh0, bh0, acc[t], 0, 0, 0);
    acc[t] = MFMA16(Gh0, bl0, acc[t], 0, 0, 0);
    acc[t] = MFMA16(Gl0, bh0, acc[t], 0, 0, 0);
    acc[t] = MFMA16(Gh1, bh1, acc[t], 0, 0, 0);
    acc[t] = MFMA16(Gh1, bl1, acc[t], 0, 0, 0);
    acc[t] = MFMA16(Gl1, bh1, acc[t], 0, 0, 0);
  }
  if (HASP) {
#pragma unroll
    for (int t = 12; t < 24; ++t) {
      const short8* bh0p = (const short8*)(WGhi + ((t << 1) << 9)) + lane;
      const short8* bl0p = (const short8*)(WGlo + ((t << 1) << 9)) + lane;
      const short8* bh1p = (const short8*)(WGhi + (((t << 1) + 1) << 9)) + lane;
      const short8* bl1p = (const short8*)(WGlo + (((t << 1) + 1) << 9)) + lane;
      short8 bh0 = *bh0p, bl0 = *bl0p, bh1 = *bh1p, bl1 = *bl1p;
      acc[t] = MFMA16(Ph0, bh0, acc[t], 0, 0, 0);
      acc[t] = MFMA16(Ph0, bl0, acc[t], 0, 0, 0);
      acc[t] = MFMA16(Pl0, bh0, acc[t], 0, 0, 0);
      acc[t] = MFMA16(Ph1, bh1, acc[t], 0, 0, 0);
      acc[t] = MFMA16(Ph1, bl1, acc[t], 0, 0, 0);
      acc[t] = MFMA16(Pl1, bh1, acc[t], 0, 0, 0);
    }
  }
  int rbase = (wv << 4) + ((lane >> 4) << 2);
#pragma unroll
  for (int ct = 0; ct < 4; ++ct) {
    int c = (ct << 4) + nl;
#pragma unroll
    for (int reg = 0; reg < 4; ++reg) {
      size_t rowg = m0 + rbase + reg;
      float rg = sigf(acc[ct][reg]      + acc[12 + ct][reg]);
      float zg = sigf(acc[4 + ct][reg]  + acc[16 + ct][reg]);
      float ng = tanhfast(acc[8 + ct][reg] + rg * acc[20 + ct][reg]);
      float hv = HASP ? hp[(rowg << 6) + c] : 0.f;
      hout[(rowg << 6) + c] = (1.f - zg) * ng + zg * hv;
    }
  }
}

// ---------------------------------------------------------------------------
__global__ __launch_bounds__(256) void k_heads(
    const float* __restrict__ Xb,
    const float* __restrict__ oW1, const float* __restrict__ ob1,
    const float* __restrict__ oW2, const float* __restrict__ ob2,
    const float* __restrict__ dW1, const float* __restrict__ db1,
    const float* __restrict__ dW2, const float* __restrict__ db2,
    float* __restrict__ out) {
  __shared__ float w1o[Hh * HB2], w1d[Hh * HB2];
  __shared__ float w2o[HB2], w2d[HB2], b1o[HB2], b1d[HB2];
  int tid = threadIdx.x;
  for (int idx = tid; idx < Hh * HB2; idx += 256) { w1o[idx] = oW1[idx]; w1d[idx] = dW1[idx]; }
  if (tid < HB2) { w2o[tid] = oW2[tid]; w2d[tid] = dW2[tid]; b1o[tid] = ob1[tid]; b1d[tid] = db1[tid]; }
  __syncthreads();
  int r = blockIdx.x * 256 + tid;
  int b = r >> 11, n = r & (Nn - 1);
  const float* xrow = Xb + (((size_t)b * Ss + (Ss - 1)) * Nn + n) * Hh;
  float x[Hh];
  const float4* xp = (const float4*)xrow;
#pragma unroll
  for (int q = 0; q < Hh / 4; ++q) {
    float4 v = xp[q];
    x[4*q] = v.x; x[4*q+1] = v.y; x[4*q+2] = v.z; x[4*q+3] = v.w;
  }
  float acco = ob2[0], accd = db2[0];
  for (int j = 0; j < HB2; ++j) {
    float ho = b1o[j], hd = b1d[j];
#pragma unroll
    for (int k = 0; k < Hh; ++k) {
      ho += x[k] * w1o[k * HB2 + j];
      hd += x[k] * w1d[k * HB2 + j];
    }
    acco += fmaxf(ho, 0.f) * w2o[j];
    accd += fmaxf(hd, 0.f) * w2d[j];
  }
  out[r] = acco;
  out[Bb * Nn + r] = accd;
}

// ---------------------------------------------------------------------------
extern "C" void kernel_launch(void* const* d_in, const int* in_sizes, int n_in,
                              void* d_out, int out_size, void* d_ws, size_t ws_size,
                              hipStream_t stream) {
  const float* x   = (const float*)d_in[0];
  const int*   ei  = (const int*)d_in[1];
  const float* ea  = (const float*)d_in[2];
  const float* Wp  = (const float*)d_in[3];
  const float* bp  = (const float*)d_in[4];
  const float* Wl  = (const float*)d_in[5];
  const float* bl  = (const float*)d_in[6];
  const float* Wr  = (const float*)d_in[7];
  const float* br  = (const float*)d_in[8];
  const float* We  = (const float*)d_in[9];
  const float* att = (const float*)d_in[10];
  const float* gb  = (const float*)d_in[11];
  const float* Wih = (const float*)d_in[12];
  const float* Whh = (const float*)d_in[13];
  const float* bih = (const float*)d_in[14];
  const float* bhh = (const float*)d_in[15];
  const float* oW1 = (const float*)d_in[16];
  const float* ob1 = (const float*)d_in[17];
  const float* oW2 = (const float*)d_in[18];
  const float* ob2 = (const float*)d_in[19];
  const float* dW1 = (const float*)d_in[20];
  const float* db1 = (const float*)d_in[21];
  const float* dW2 = (const float*)d_in[22];
  const float* db2 = (const float*)d_in[23];
  float* out = (float*)d_out;

  // workspace layout
  float* f    = (float*)d_ws;
  float* Xb   = f;                          // RTOT*64
  float* XLb  = Xb  + (size_t)RTOT * Hh;
  float* XRb  = XLb + (size_t)RTOT * Hh;    // hg after k_gat
  float* EPc  = XRb + (size_t)RTOT * Hh;    // E2c*64 (CSR order)
  unsigned short* WXhi = (unsigned short*)(EPc + (size_t)E2c * Hh); // 16384
  unsigned short* WXlo = WXhi + 16384;
  unsigned short* WGhi = WXlo + 16384;      // 49152
  unsigned short* WGlo = WGhi + 49152;
  float* cntF = (float*)(WGlo + 49152);     // 2048
  float* loopA = cntF + Nn;                 // 2048*8
  int*   fillI = (int*)(loopA + Nn * EFf);  // 2048
  int*   offs  = fillI + Nn;                // 2049 (+pad)
  int*   posOf = offs + 2052;               // 18432
  int*   srcA  = posOf + E2c;               // 18432

  hipMemsetAsync(cntF, 0, (size_t)(Nn + Nn * EFf + Nn) * 4, stream);

  k_loop_accum<<<dim3(Ee * EFf / 256), 256, 0, stream>>>(ei, ea, cntF, loopA);
  k_loop_div<<<dim3(Nn * EFf / 256), 256, 0, stream>>>(loopA, cntF);
  k_scan<<<1, 256, 0, stream>>>(cntF, offs);
  k_scatter<<<dim3((E2c + 255) / 256), 256, 0, stream>>>(ei, offs, fillI, posOf, srcA);
  k_wprep<<<dim3(256), 256, 0, stream>>>(Wl, Wr, Wih, Whh, WXhi, WXlo, WGhi, WGlo);

  // X = x @ Wp + bp
  k_proj<<<dim3(RTOT / 512, 4), 256, 0, stream>>>(x, Wp, bp, Xb);

  for (int l = 0; l < 2; ++l) {
    k_ep<<<dim3(E2c * Hh / 256), 256, 0, stream>>>(
        ea, loopA, We + (size_t)l * EFf * Hh, posOf, EPc);
    k_xlr_mm<<<dim3(RTOT / 64), 256, 0, stream>>>(
        Xb, WXhi + (size_t)l * 8192, WXlo + (size_t)l * 8192,
        bl + (size_t)l * Hh, br + (size_t)l * Hh, XLb, XRb);
    k_gat<<<dim3(RTOT * Hh / 256), 256, 0, stream>>>(
        XLb, XRb, EPc, offs, srcA, att + (size_t)l * Hh, gb + (size_t)l * Hh);
    const unsigned short* WGh_l = WGhi + (size_t)l * 24576;
    const unsigned short* WGl_l = WGlo + (size_t)l * 24576;
    const float* bih_l = bih + (size_t)l * 192;
    const float* bhh_l = bhh + (size_t)l * 192;
    for (int t = 0; t < Bb; ++t) {
      const float* hg_t = XRb + (size_t)t * Mm * Hh;
      float* h_out = Xb + (size_t)t * Mm * Hh;
      if (t == 0) {
        k_gru_mm<0><<<dim3(Mm / 64), 256, 0, stream>>>(
            hg_t, nullptr, WGh_l, WGl_l, bih_l, bhh_l, h_out);
      } else {
        const float* h_prev = Xb + (size_t)(t - 1) * Mm * Hh;
        k_gru_mm<1><<<dim3(Mm / 64), 256, 0, stream>>>(
            hg_t, h_prev, WGh_l, WGl_l, bih_l, bhh_l, h_out);
      }
    }
  }

  k_heads<<<dim3(Bb * Nn / 256), 256, 0, stream>>>(
      Xb, oW1, ob1, oW2, ob2, dW1, db1, dW2, db2, out);
}

// Round 11
// 495.216 us; speedup vs baseline: 2.6188x; 1.0232x over previous
//
#include <hip/hip_runtime.h>
#include <math.h>

#define Bb   4
#define Ss   16
#define Nn   2048
#define Ff   32
#define Ee   16384
#define EFf  8
#define Hh   64
#define HB2  32
#define E2c  (Ee + Nn)          // 18432
#define RTOT (Bb*Ss*Nn)         // 131072
#define Mm   (Ss*Nn)            // 32768

typedef __attribute__((ext_vector_type(8))) short short8;
typedef __attribute__((ext_vector_type(4))) float f32x4;
#define MFMA16 __builtin_amdgcn_mfma_f32_16x16x32_bf16

__device__ __forceinline__ float sigf(float x) { return 1.f / (1.f + __expf(-x)); }
__device__ __forceinline__ float tanhfast(float x) { return 2.f / (1.f + __expf(-2.f * x)) - 1.f; }

// round-to-nearest-even bf16 split: x ~= hi + lo (each bf16)
__device__ __forceinline__ void split_bf16(float x, unsigned short& h, unsigned short& l) {
  unsigned u = __float_as_uint(x);
  unsigned r = (u + 0x7FFFu + ((u >> 16) & 1u)) >> 16;
  h = (unsigned short)r;
  float rest = x - __uint_as_float(r << 16);
  unsigned u2 = __float_as_uint(rest);
  l = (unsigned short)((u2 + 0x7FFFu + ((u2 >> 16) & 1u)) >> 16);
}

template <int PAT>
__device__ __forceinline__ float xorf(float v) {
  return __int_as_float(__builtin_amdgcn_ds_swizzle(__float_as_int(v), PAT));
}

// ---------------------------------------------------------------------------
__global__ __launch_bounds__(256) void k_loop_accum(
    const int* __restrict__ ei, const float* __restrict__ ea,
    float* __restrict__ cntF, float* __restrict__ loopA) {
  int idx = blockIdx.x * 256 + threadIdx.x;
  int e = idx >> 3, j = idx & 7;
  int d = ei[Ee + e];
  atomicAdd(&loopA[d * EFf + j], ea[idx]);
  if (j == 0) atomicAdd(&cntF[d], 1.0f);
}

__global__ __launch_bounds__(256) void k_loop_div(
    float* __restrict__ loopA, const float* __restrict__ cntF) {
  int idx = blockIdx.x * 256 + threadIdx.x;
  loopA[idx] /= fmaxf(cntF[idx >> 3], 1.0f);
}

// ---------------------------------------------------------------------------
__global__ __launch_bounds__(256) void k_scan(
    const float* __restrict__ cntF, int* __restrict__ offs) {
  __shared__ int partial[256];
  int tid = threadIdx.x;
  int base = tid * 8;
  int vals[8];
  int s = 0;
  for (int i = 0; i < 8; ++i) {
    int c = (int)cntF[base + i] + 1;
    vals[i] = c;
    s += c;
  }
  partial[tid] = s;
  __syncthreads();
  for (int off = 1; off < 256; off <<= 1) {
    int v = partial[tid];
    int add = (tid >= off) ? partial[tid - off] : 0;
    __syncthreads();
    partial[tid] = v + add;
    __syncthreads();
  }
  int run = (tid == 0) ? 0 : partial[tid - 1];
  for (int i = 0; i < 8; ++i) {
    offs[base + i] = run;
    run += vals[i];
  }
  if (tid == 255) offs[Nn] = run;
}

__global__ __launch_bounds__(256) void k_scatter(
    const int* __restrict__ ei, const int* __restrict__ offs,
    int* __restrict__ fillI, int* __restrict__ posOf, int* __restrict__ srcA) {
  int e = blockIdx.x * 256 + threadIdx.x;
  if (e >= E2c) return;
  int d = (e < Ee) ? ei[Ee + e] : (e - Ee);
  int s = (e < Ee) ? ei[e]      : (e - Ee);
  int pos = offs[d] + atomicAdd(&fillI[d], 1);
  posOf[e] = pos;
  srcA[pos] = s;
}

// ---------------------------------------------------------------------------
// Pre-split + pre-swizzle weights into MFMA B-fragment order (see R9).
// ---------------------------------------------------------------------------
__global__ __launch_bounds__(256) void k_wprep(
    const float* __restrict__ Wl, const float* __restrict__ Wr,
    const float* __restrict__ Wih, const float* __restrict__ Whh,
    unsigned short* __restrict__ WXhi, unsigned short* __restrict__ WXlo,
    unsigned short* __restrict__ WGhi, unsigned short* __restrict__ WGlo) {
  int idx = blockIdx.x * 256 + threadIdx.x;   // 65536 total
  if (idx < 16384) {
    int j = idx & 7, lane = (idx >> 3) & 63, kh = (idx >> 9) & 1;
    int t = (idx >> 10) & 7, l = idx >> 13;
    int n = t * 16 + (lane & 15);
    int k = kh * 32 + ((lane >> 4) << 3) + j;
    const float* W = (n < 64) ? (Wl + (size_t)l * 4096) : (Wr + (size_t)l * 4096);
    float v = W[k * 64 + (n & 63)];
    unsigned short h, lo;
    split_bf16(v, h, lo);
    WXhi[idx] = h; WXlo[idx] = lo;
  } else {
    int i2 = idx - 16384;                     // < 49152
    int j = i2 & 7, lane = (i2 >> 3) & 63, kh = (i2 >> 9) & 1;
    int t = (i2 >> 10) % 24, l = i2 / 24576;
    int n = t * 16 + (lane & 15);
    int k = kh * 32 + ((lane >> 4) << 3) + j;
    int g = n >> 6, c = n & 63;
    const float* W = (g < 3) ? (Wih + (size_t)l * 12288 + (size_t)(g * 64 + c) * 64)
                             : (Whh + (size_t)l * 12288 + (size_t)((g - 3) * 64 + c) * 64);
    float v = W[k];
    unsigned short h, lo;
    split_bf16(v, h, lo);
    WGhi[i2] = h; WGlo[i2] = lo;
  }
}

// ---------------------------------------------------------------------------
__global__ __launch_bounds__(256) void k_ep(
    const float* __restrict__ ea, const float* __restrict__ loopA,
    const float* __restrict__ We, const int* __restrict__ posOf,
    float* __restrict__ EPc) {
  __shared__ float wlds[EFf * Hh];
  int tid = threadIdx.x;
  if (tid < EFf * Hh) wlds[tid] = We[tid];
  if (tid + 256 < EFf * Hh) wlds[tid + 256] = We[tid + 256];
  __syncthreads();
  int idx = blockIdx.x * 256 + tid;
  int e = idx >> 6, j = idx & 63;
  const float* a = (e < Ee) ? (ea + (size_t)e * EFf) : (loopA + (size_t)(e - Ee) * EFf);
  float acc = 0.f;
#pragma unroll
  for (int k = 0; k < EFf; ++k) acc += a[k] * wlds[k * Hh + j];
  EPc[(((size_t)posOf[e]) << 6) + j] = acc;
}

// ---------------------------------------------------------------------------
// proj (R5 version): thread = 2 rows x 16 cols. grid (RTOT/512, 4)
// ---------------------------------------------------------------------------
__global__ __launch_bounds__(256) void k_proj(
    const float* __restrict__ X, const float* __restrict__ Wp,
    const float* __restrict__ bp, float* __restrict__ Out) {
  __shared__ float w[32 * 16];
  int tid = threadIdx.x;
  int j0 = blockIdx.y << 4;
  for (int idx = tid; idx < 32 * 16; idx += 256)
    w[idx] = Wp[((idx >> 4) << 6) + j0 + (idx & 15)];
  __syncthreads();
  int r0 = (blockIdx.x << 9) + tid;
  float acc[2][16];
#pragma unroll
  for (int jj = 0; jj < 16; ++jj) { float b = bp[j0 + jj]; acc[0][jj] = b; acc[1][jj] = b; }
  const float* x0 = X + ((size_t)r0 << 5);
  const float* x1 = x0 + (256 << 5);
  for (int kc = 0; kc < 8; ++kc) {
    float4 a0 = *(const float4*)(x0 + 4 * kc);
    float4 a1 = *(const float4*)(x1 + 4 * kc);
    float a0a[4] = {a0.x, a0.y, a0.z, a0.w};
    float a1a[4] = {a1.x, a1.y, a1.z, a1.w};
#pragma unroll
    for (int q = 0; q < 4; ++q) {
      const float4* wp4 = (const float4*)(w + ((4 * kc + q) << 4));
#pragma unroll
      for (int q4 = 0; q4 < 4; ++q4) {
        float4 wv = wp4[q4];
        acc[0][4*q4+0] = fmaf(a0a[q], wv.x, acc[0][4*q4+0]);
        acc[0][4*q4+1] = fmaf(a0a[q], wv.y, acc[0][4*q4+1]);
        acc[0][4*q4+2] = fmaf(a0a[q], wv.z, acc[0][4*q4+2]);
        acc[0][4*q4+3] = fmaf(a0a[q], wv.w, acc[0][4*q4+3]);
        acc[1][4*q4+0] = fmaf(a1a[q], wv.x, acc[1][4*q4+0]);
        acc[1][4*q4+1] = fmaf(a1a[q], wv.y, acc[1][4*q4+1]);
        acc[1][4*q4+2] = fmaf(a1a[q], wv.z, acc[1][4*q4+2]);
        acc[1][4*q4+3] = fmaf(a1a[q], wv.w, acc[1][4*q4+3]);
      }
    }
  }
#pragma unroll
  for (int rr = 0; rr < 2; ++rr) {
    float* op = Out + (((size_t)(r0 + 256 * rr)) << 6) + j0;
#pragma unroll
    for (int q4 = 0; q4 < 4; ++q4)
      *(float4*)(op + 4 * q4) = make_float4(acc[rr][4*q4], acc[rr][4*q4+1], acc[rr][4*q4+2], acc[rr][4*q4+3]);
  }
}

// ---------------------------------------------------------------------------
// XL/XR via bf16x3 MFMA (R9, measured good).
// ---------------------------------------------------------------------------
__global__ __launch_bounds__(256) void k_xlr_mm(
    const float* __restrict__ X,
    const unsigned short* __restrict__ WXhi, const unsigned short* __restrict__ WXlo,
    const float* __restrict__ bl_, const float* __restrict__ br_,
    float* __restrict__ XL, float* __restrict__ XR) {
  __shared__ unsigned short ahi[4096], alo[4096];
  int tid = threadIdx.x, lane = tid & 63, wv = tid >> 6;
  size_t m0 = (size_t)blockIdx.x << 6;
  for (int i = 0; i < 16; ++i) {
    int el = (i << 8) + tid, row = el >> 6, c = el & 63;
    float x = X[((m0 + row) << 6) + c];
    unsigned short h, lo;
    split_bf16(x, h, lo);
    int fa = ((((c >> 5) << 2) + (row >> 4)) * 64 + (((c >> 3) & 3) << 4) + (row & 15)) * 8 + (c & 7);
    ahi[fa] = h; alo[fa] = lo;
  }
  __syncthreads();
  short8 Ah0 = *(const short8*)&ahi[((0 + wv) << 6 | lane) << 3];
  short8 Al0 = *(const short8*)&alo[((0 + wv) << 6 | lane) << 3];
  short8 Ah1 = *(const short8*)&ahi[((4 + wv) << 6 | lane) << 3];
  short8 Al1 = *(const short8*)&alo[((4 + wv) << 6 | lane) << 3];
  int nl = lane & 15;
  f32x4 acc[8];
#pragma unroll
  for (int t = 0; t < 8; ++t) {
    int n = t * 16 + nl;
    float b = (n < 64) ? bl_[n] : br_[n - 64];
    acc[t] = (f32x4){b, b, b, b};
  }
#pragma unroll
  for (int t = 0; t < 8; ++t) {
    const short8* bh0p = (const short8*)(WXhi + ((t << 1) << 9)) + lane;
    const short8* bl0p = (const short8*)(WXlo + ((t << 1) << 9)) + lane;
    const short8* bh1p = (const short8*)(WXhi + (((t << 1) + 1) << 9)) + lane;
    const short8* bl1p = (const short8*)(WXlo + (((t << 1) + 1) << 9)) + lane;
    short8 bh0 = *bh0p, bl0 = *bl0p, bh1 = *bh1p, bl1 = *bl1p;
    acc[t] = MFMA16(Ah0, bh0, acc[t], 0, 0, 0);
    acc[t] = MFMA16(Ah0, bl0, acc[t], 0, 0, 0);
    acc[t] = MFMA16(Al0, bh0, acc[t], 0, 0, 0);
    acc[t] = MFMA16(Ah1, bh1, acc[t], 0, 0, 0);
    acc[t] = MFMA16(Ah1, bl1, acc[t], 0, 0, 0);
    acc[t] = MFMA16(Al1, bh1, acc[t], 0, 0, 0);
  }
  int rbase = (wv << 4) + ((lane >> 4) << 2);
#pragma unroll
  for (int t = 0; t < 8; ++t) {
    int n = t * 16 + nl;
    float* out = (n < 64) ? (XL + (m0 << 6) + n) : (XR + (m0 << 6) + (n - 64));
#pragma unroll
    for (int reg = 0; reg < 4; ++reg)
      out[(size_t)(rbase + reg) << 6] = acc[t][reg];
  }
}

// ---------------------------------------------------------------------------
// GATv2 v4: wave per (g,d); lane = (eSub 0..7, hOct 0..7). Each lane owns 8
// h-components of one edge in a chunk of 8. Logit dot = 8 lane-local FMA +
// 3-step reduce within 8 lanes (2 DPP quad_perm + swizzle xor4). Final
// cross-group butterfly (xor8/16/32) once per wave. No 64-edge cap.
// ---------------------------------------------------------------------------
__global__ __launch_bounds__(256) void k_gat(
    const float* __restrict__ XL, float* __restrict__ XR_HG,
    const float* __restrict__ EPc, const int* __restrict__ offs,
    const int* __restrict__ srcA,
    const float* __restrict__ att, const float* __restrict__ gbl) {
  int gw = (blockIdx.x * 256 + threadIdx.x) >> 6;
  int lane = threadIdx.x & 63;
  int eSub = lane >> 3;
  int hOct = lane & 7;
  int g = gw >> 11;
  int d = gw & (Nn - 1);
  size_t rowbase = ((size_t)gw) << 6;
  const float* xrp = XR_HG + rowbase + (hOct << 3);
  float4 xr0 = *(const float4*)(xrp);
  float4 xr1 = *(const float4*)(xrp + 4);
  float4 at0 = *(const float4*)(att + (hOct << 3));
  float4 at1 = *(const float4*)(att + (hOct << 3) + 4);
  int p0 = offs[d], p1 = offs[d + 1];
  int nE = p1 - p0;
  const float* XLg = XL + (((size_t)g * Nn) << 6);
  float Ssum = 0.f;
  float4 acc0 = make_float4(0.f, 0.f, 0.f, 0.f);
  float4 acc1 = make_float4(0.f, 0.f, 0.f, 0.f);
  int nCh = (nE + 7) >> 3;
  for (int c = 0; c < nCh; ++c) {
    int p = (c << 3) + eSub;
    int pc = p < nE ? p : nE - 1;
    int s = srcA[p0 + pc];
    const float* xlp = XLg + ((size_t)s << 6) + (hOct << 3);
    float4 xl0 = *(const float4*)(xlp);
    float4 xl1 = *(const float4*)(xlp + 4);
    const float* epp = EPc + (((size_t)(p0 + pc)) << 6) + (hOct << 3);
    float4 ep0 = *(const float4*)(epp);
    float4 ep1 = *(const float4*)(epp + 4);
    float m, v = 0.f;
    m = xl0.x + xr0.x + ep0.x; m = fmaxf(m, 0.2f * m); v = fmaf(m, at0.x, v);
    m = xl0.y + xr0.y + ep0.y; m = fmaxf(m, 0.2f * m); v = fmaf(m, at0.y, v);
    m = xl0.z + xr0.z + ep0.z; m = fmaxf(m, 0.2f * m); v = fmaf(m, at0.z, v);
    m = xl0.w + xr0.w + ep0.w; m = fmaxf(m, 0.2f * m); v = fmaf(m, at0.w, v);
    m = xl1.x + xr1.x + ep1.x; m = fmaxf(m, 0.2f * m); v = fmaf(m, at1.x, v);
    m = xl1.y + xr1.y + ep1.y; m = fmaxf(m, 0.2f * m); v = fmaf(m, at1.y, v);
    m = xl1.z + xr1.z + ep1.z; m = fmaxf(m, 0.2f * m); v = fmaf(m, at1.z, v);
    m = xl1.w + xr1.w + ep1.w; m = fmaxf(m, 0.2f * m); v = fmaf(m, at1.w, v);
    int xi;
    xi = __builtin_amdgcn_update_dpp(0, __float_as_int(v), 0xB1, 0xF, 0xF, true);  // xor1
    v += __int_as_float(xi);
    xi = __builtin_amdgcn_update_dpp(0, __float_as_int(v), 0x4E, 0xF, 0xF, true);  // xor2
    v += __int_as_float(xi);
    v += xorf<0x101F>(v);                                                          // xor4
    float w = (p < nE) ? __expf(v) : 0.f;
    Ssum += w;
    acc0.x = fmaf(w, xl0.x, acc0.x);
    acc0.y = fmaf(w, xl0.y, acc0.y);
    acc0.z = fmaf(w, xl0.z, acc0.z);
    acc0.w = fmaf(w, xl0.w, acc0.w);
    acc1.x = fmaf(w, xl1.x, acc1.x);
    acc1.y = fmaf(w, xl1.y, acc1.y);
    acc1.z = fmaf(w, xl1.z, acc1.z);
    acc1.w = fmaf(w, xl1.w, acc1.w);
  }
  // cross-group butterfly: xor8, xor16 (swizzle), xor32 (shfl)
  acc0.x += xorf<0x201F>(acc0.x); acc0.y += xorf<0x201F>(acc0.y);
  acc0.z += xorf<0x201F>(acc0.z); acc0.w += xorf<0x201F>(acc0.w);
  acc1.x += xorf<0x201F>(acc1.x); acc1.y += xorf<0x201F>(acc1.y);
  acc1.z += xorf<0x201F>(acc1.z); acc1.w += xorf<0x201F>(acc1.w);
  Ssum   += xorf<0x201F>(Ssum);
  acc0.x += xorf<0x401F>(acc0.x); acc0.y += xorf<0x401F>(acc0.y);
  acc0.z += xorf<0x401F>(acc0.z); acc0.w += xorf<0x401F>(acc0.w);
  acc1.x += xorf<0x401F>(acc1.x); acc1.y += xorf<0x401F>(acc1.y);
  acc1.z += xorf<0x401F>(acc1.z); acc1.w += xorf<0x401F>(acc1.w);
  Ssum   += xorf<0x401F>(Ssum);
  acc0.x += __shfl_xor(acc0.x, 32, 64); acc0.y += __shfl_xor(acc0.y, 32, 64);
  acc0.z += __shfl_xor(acc0.z, 32, 64); acc0.w += __shfl_xor(acc0.w, 32, 64);
  acc1.x += __shfl_xor(acc1.x, 32, 64); acc1.y += __shfl_xor(acc1.y, 32, 64);
  acc1.z += __shfl_xor(acc1.z, 32, 64); acc1.w += __shfl_xor(acc1.w, 32, 64);
  Ssum   += __shfl_xor(Ssum,   32, 64);
  if (eSub == 0) {
    float inv = 1.f / Ssum;
    float4 g0 = *(const float4*)(gbl + (hOct << 3));
    float4 g1 = *(const float4*)(gbl + (hOct << 3) + 4);
    float* op = XR_HG + rowbase + (hOct << 3);
    *(float4*)(op)     = make_float4(fmaf(acc0.x, inv, g0.x), fmaf(acc0.y, inv, g0.y),
                                     fmaf(acc0.z, inv, g0.z), fmaf(acc0.w, inv, g0.w));
    *(float4*)(op + 4) = make_float4(fmaf(acc1.x, inv, g1.x), fmaf(acc1.y, inv, g1.y),
                                     fmaf(acc1.z, inv, g1.z), fmaf(acc1.w, inv, g1.w));
  }
}

// ---------------------------------------------------------------------------
// Fused GRU step via bf16x3 MFMA (R9, measured good).
// ---------------------------------------------------------------------------
template <int HASP>
__global__ __launch_bounds__(256) void k_gru_mm(
    const float* __restrict__ hg, const float* __restrict__ hp,
    const unsigned short* __restrict__ WGhi, const unsigned short* __restrict__ WGlo,
    const float* __restrict__ bih, const float* __restrict__ bhh,
    float* __restrict__ hout) {
  __shared__ unsigned short ghi[4096], glo[4096], phi[4096], plo[4096];
  int tid = threadIdx.x, lane = tid & 63, wv = tid >> 6;
  size_t m0 = (size_t)blockIdx.x << 6;
  for (int i = 0; i < 16; ++i) {
    int el = (i << 8) + tid, row = el >> 6, c = el & 63;
    int fa = ((((c >> 5) << 2) + (row >> 4)) * 64 + (((c >> 3) & 3) << 4) + (row & 15)) * 8 + (c & 7);
    float xg = hg[((m0 + row) << 6) + c];
    unsigned short h, lo;
    split_bf16(xg, h, lo);
    ghi[fa] = h; glo[fa] = lo;
    if (HASP) {
      float xp = hp[((m0 + row) << 6) + c];
      split_bf16(xp, h, lo);
      phi[fa] = h; plo[fa] = lo;
    }
  }
  __syncthreads();
  short8 Gh0 = *(const short8*)&ghi[((0 + wv) << 6 | lane) << 3];
  short8 Gl0 = *(const short8*)&glo[((0 + wv) << 6 | lane) << 3];
  short8 Gh1 = *(const short8*)&ghi[((4 + wv) << 6 | lane) << 3];
  short8 Gl1 = *(const short8*)&glo[((4 + wv) << 6 | lane) << 3];
  short8 Ph0, Pl0, Ph1, Pl1;
  if (HASP) {
    Ph0 = *(const short8*)&phi[((0 + wv) << 6 | lane) << 3];
    Pl0 = *(const short8*)&plo[((0 + wv) << 6 | lane) << 3];
    Ph1 = *(const short8*)&phi[((4 + wv) << 6 | lane) << 3];
    Pl1 = *(const short8*)&plo[((4 + wv) << 6 | lane) << 3];
  }
  int nl = lane & 15;
  f32x4 acc[24];
#pragma unroll
  for (int t = 0; t < 24; ++t) {
    int g = t >> 2;
    int c = ((t & 3) << 4) + nl;
    float b = (g < 3) ? bih[(g << 6) + c] : bhh[((g - 3) << 6) + c];
    acc[t] = (f32x4){b, b, b, b};
  }
#pragma unroll
  for (int t = 0; t < 12; ++t) {
    const short8* bh0p = (const short8*)(WGhi + ((t << 1) << 9)) + lane;
    const short8* bl0p = (const short8*)(WGlo + ((t << 1) << 9)) + lane;
    const short8* bh1p = (const short8*)(WGhi + (((t << 1) + 1) << 9)) + lane;
    const short8* bl1p = (const short8*)(WGlo + (((t << 1) + 1) << 9)) + lane;
    short8 bh0 = *bh0p, bl0 = *bl0p, bh1 = *bh1p, bl1 = *bl1p;
    acc[t] = MFMA16(Gh0, bh0, acc[t], 0, 0, 0);
    acc[t] = MFMA16(Gh0, bl0, acc[t], 0, 0, 0);
    acc[t] = MFMA16(Gl0, bh0, acc[t], 0, 0, 0);
    acc[t] = MFMA16(Gh1, bh1, acc[t], 0, 0, 0);
    acc[t] = MFMA16(Gh1, bl1, acc[t], 0, 0, 0);
    acc[t] = MFMA16(Gl1, bh1, acc[t], 0, 0, 0);
  }
  if (HASP) {
#pragma unroll
    for (int t = 12; t < 24; ++t) {
      const short8* bh0p = (const short8*)(WGhi + ((t << 1) << 9)) + lane;
      const short8* bl0p = (const short8*)(WGlo + ((t << 1) << 9)) + lane;
      const short8* bh1p = (const short8*)(WGhi + (((t << 1) + 1) << 9)) + lane;
      const short8* bl1p = (const short8*)(WGlo + (((t << 1) + 1) << 9)) + lane;
      short8 bh0 = *bh0p, bl0 = *bl0p, bh1 = *bh1p, bl1 = *bl1p;
      acc[t] = MFMA16(Ph0, bh0, acc[t], 0, 0, 0);
      acc[t] = MFMA16(Ph0, bl0, acc[t], 0, 0, 0);
      acc[t] = MFMA16(Pl0, bh0, acc[t], 0, 0, 0);
      acc[t] = MFMA16(Ph1, bh1, acc[t], 0, 0, 0);
      acc[t] = MFMA16(Ph1, bl1, acc[t], 0, 0, 0);
      acc[t] = MFMA16(Pl1, bh1, acc[t], 0, 0, 0);
    }
  }
  int rbase = (wv << 4) + ((lane >> 4) << 2);
#pragma unroll
  for (int ct = 0; ct < 4; ++ct) {
    int c = (ct << 4) + nl;
#pragma unroll
    for (int reg = 0; reg < 4; ++reg) {
      size_t rowg = m0 + rbase + reg;
      float rg = sigf(acc[ct][reg]      + acc[12 + ct][reg]);
      float zg = sigf(acc[4 + ct][reg]  + acc[16 + ct][reg]);
      float ng = tanhfast(acc[8 + ct][reg] + rg * acc[20 + ct][reg]);
      float hv = HASP ? hp[(rowg << 6) + c] : 0.f;
      hout[(rowg << 6) + c] = (1.f - zg) * ng + zg * hv;
    }
  }
}

// ---------------------------------------------------------------------------
__global__ __launch_bounds__(256) void k_heads(
    const float* __restrict__ Xb,
    const float* __restrict__ oW1, const float* __restrict__ ob1,
    const float* __restrict__ oW2, const float* __restrict__ ob2,
    const float* __restrict__ dW1, const float* __restrict__ db1,
    const float* __restrict__ dW2, const float* __restrict__ db2,
    float* __restrict__ out) {
  __shared__ float w1o[Hh * HB2], w1d[Hh * HB2];
  __shared__ float w2o[HB2], w2d[HB2], b1o[HB2], b1d[HB2];
  int tid = threadIdx.x;
  for (int idx = tid; idx < Hh * HB2; idx += 256) { w1o[idx] = oW1[idx]; w1d[idx] = dW1[idx]; }
  if (tid < HB2) { w2o[tid] = oW2[tid]; w2d[tid] = dW2[tid]; b1o[tid] = ob1[tid]; b1d[tid] = db1[tid]; }
  __syncthreads();
  int r = blockIdx.x * 256 + tid;
  int b = r >> 11, n = r & (Nn - 1);
  const float* xrow = Xb + (((size_t)b * Ss + (Ss - 1)) * Nn + n) * Hh;
  float x[Hh];
  const float4* xp = (const float4*)xrow;
#pragma unroll
  for (int q = 0; q < Hh / 4; ++q) {
    float4 v = xp[q];
    x[4*q] = v.x; x[4*q+1] = v.y; x[4*q+2] = v.z; x[4*q+3] = v.w;
  }
  float acco = ob2[0], accd = db2[0];
  for (int j = 0; j < HB2; ++j) {
    float ho = b1o[j], hd = b1d[j];
#pragma unroll
    for (int k = 0; k < Hh; ++k) {
      ho += x[k] * w1o[k * HB2 + j];
      hd += x[k] * w1d[k * HB2 + j];
    }
    acco += fmaxf(ho, 0.f) * w2o[j];
    accd += fmaxf(hd, 0.f) * w2d[j];
  }
  out[r] = acco;
  out[Bb * Nn + r] = accd;
}

// ---------------------------------------------------------------------------
extern "C" void kernel_launch(void* const* d_in, const int* in_sizes, int n_in,
                              void* d_out, int out_size, void* d_ws, size_t ws_size,
                              hipStream_t stream) {
  const float* x   = (const float*)d_in[0];
  const int*   ei  = (const int*)d_in[1];
  const float* ea  = (const float*)d_in[2];
  const float* Wp  = (const float*)d_in[3];
  const float* bp  = (const float*)d_in[4];
  const float* Wl  = (const float*)d_in[5];
  const float* bl  = (const float*)d_in[6];
  const float* Wr  = (const float*)d_in[7];
  const float* br  = (const float*)d_in[8];
  const float* We  = (const float*)d_in[9];
  const float* att = (const float*)d_in[10];
  const float* gb  = (const float*)d_in[11];
  const float* Wih = (const float*)d_in[12];
  const float* Whh = (const float*)d_in[13];
  const float* bih = (const float*)d_in[14];
  const float* bhh = (const float*)d_in[15];
  const float* oW1 = (const float*)d_in[16];
  const float* ob1 = (const float*)d_in[17];
  const float* oW2 = (const float*)d_in[18];
  const float* ob2 = (const float*)d_in[19];
  const float* dW1 = (const float*)d_in[20];
  const float* db1 = (const float*)d_in[21];
  const float* dW2 = (const float*)d_in[22];
  const float* db2 = (const float*)d_in[23];
  float* out = (float*)d_out;

  // workspace layout
  float* f    = (float*)d_ws;
  float* Xb   = f;                          // RTOT*64
  float* XLb  = Xb  + (size_t)RTOT * Hh;
  float* XRb  = XLb + (size_t)RTOT * Hh;    // hg after k_gat
  float* EPc  = XRb + (size_t)RTOT * Hh;    // E2c*64 (CSR order)
  unsigned short* WXhi = (unsigned short*)(EPc + (size_t)E2c * Hh); // 16384
  unsigned short* WXlo = WXhi + 16384;
  unsigned short* WGhi = WXlo + 16384;      // 49152
  unsigned short* WGlo = WGhi + 49152;
  float* cntF = (float*)(WGlo + 49152);     // 2048
  float* loopA = cntF + Nn;                 // 2048*8
  int*   fillI = (int*)(loopA + Nn * EFf);  // 2048
  int*   offs  = fillI + Nn;                // 2049 (+pad)
  int*   posOf = offs + 2052;               // 18432
  int*   srcA  = posOf + E2c;               // 18432

  hipMemsetAsync(cntF, 0, (size_t)(Nn + Nn * EFf + Nn) * 4, stream);

  k_loop_accum<<<dim3(Ee * EFf / 256), 256, 0, stream>>>(ei, ea, cntF, loopA);
  k_loop_div<<<dim3(Nn * EFf / 256), 256, 0, stream>>>(loopA, cntF);
  k_scan<<<1, 256, 0, stream>>>(cntF, offs);
  k_scatter<<<dim3((E2c + 255) / 256), 256, 0, stream>>>(ei, offs, fillI, posOf, srcA);
  k_wprep<<<dim3(256), 256, 0, stream>>>(Wl, Wr, Wih, Whh, WXhi, WXlo, WGhi, WGlo);

  // X = x @ Wp + bp
  k_proj<<<dim3(RTOT / 512, 4), 256, 0, stream>>>(x, Wp, bp, Xb);

  for (int l = 0; l < 2; ++l) {
    k_ep<<<dim3(E2c * Hh / 256), 256, 0, stream>>>(
        ea, loopA, We + (size_t)l * EFf * Hh, posOf, EPc);
    k_xlr_mm<<<dim3(RTOT / 64), 256, 0, stream>>>(
        Xb, WXhi + (size_t)l * 8192, WXlo + (size_t)l * 8192,
        bl + (size_t)l * Hh, br + (size_t)l * Hh, XLb, XRb);
    k_gat<<<dim3(RTOT * Hh / 256), 256, 0, stream>>>(
        XLb, XRb, EPc, offs, srcA, att + (size_t)l * Hh, gb + (size_t)l * Hh);
    const unsigned short* WGh_l = WGhi + (size_t)l * 24576;
    const unsigned short* WGl_l = WGlo + (size_t)l * 24576;
    const float* bih_l = bih + (size_t)l * 192;
    const float* bhh_l = bhh + (size_t)l * 192;
    for (int t = 0; t < Bb; ++t) {
      const float* hg_t = XRb + (size_t)t * Mm * Hh;
      float* h_out = Xb + (size_t)t * Mm * Hh;
      if (t == 0) {
        k_gru_mm<0><<<dim3(Mm / 64), 256, 0, stream>>>(
            hg_t, nullptr, WGh_l, WGl_l, bih_l, bhh_l, h_out);
      } else {
        const float* h_prev = Xb + (size_t)(t - 1) * Mm * Hh;
        k_gru_mm<1><<<dim3(Mm / 64), 256, 0, stream>>>(
            hg_t, h_prev, WGh_l, WGl_l, bih_l, bhh_l, h_out);
      }
    }
  }

  k_heads<<<dim3(Bb * Nn / 256), 256, 0, stream>>>(
      Xb, oW1, ob1, oW2, ob2, dW1, db1, dW2, db2, out);
}